// Round 4
// baseline (190.005 us; speedup 1.0000x reference)
//
#include <hip/hip_runtime.h>
#include <stdint.h>

typedef __attribute__((ext_vector_type(8))) short short8;
typedef __attribute__((ext_vector_type(16))) float f32x16;

#define NB 32

__device__ __forceinline__ float bf2f(uint16_t v) {
    return __uint_as_float(((uint32_t)v) << 16);
}
__device__ __forceinline__ uint16_t f2bf(float f) {
    uint32_t u = __float_as_uint(f);
    u += 0x7fffu + ((u >> 16) & 1u);   // RNE
    return (uint16_t)(u >> 16);
}

// async global(16B) -> LDS, linear dest (wave-uniform base + lane*16)
__device__ __forceinline__ void gload16(const void* g, void* l) {
    __builtin_amdgcn_global_load_lds(
        (const __attribute__((address_space(1))) uint32_t*)g,
        (__attribute__((address_space(3))) uint32_t*)l, 16, 0, 0);
}

// ---------------- conv1: Cin=3, Cout=64, 3x3 SAME, ReLU, NHWC bf16 out -----
__global__ __launch_bounds__(256) void conv1_k(
    const float* __restrict__ x, const float* __restrict__ w,
    const float* __restrict__ bias, uint16_t* __restrict__ h1)
{
    const int b = blockIdx.y;
    const int tile = blockIdx.x;                 // 16 tiles of 16x16
    const int ty0 = (tile >> 2) * 16, tx0 = (tile & 3) * 16;
    __shared__ float in_s[3][18][18];
    __shared__ float w_s[64 * 27];
    __shared__ float b_s[64];
    const int tid = threadIdx.x;
    for (int i = tid; i < 3 * 18 * 18; i += 256) {
        int c = i / 324, r2 = i % 324, yy = r2 / 18, xx = r2 % 18;
        int gy = ty0 - 1 + yy, gx = tx0 - 1 + xx;
        float v = 0.f;
        if (gy >= 0 && gy < 64 && gx >= 0 && gx < 64)
            v = x[((b * 3 + c) * 64 + gy) * 64 + gx];
        in_s[c][yy][xx] = v;
    }
    for (int i = tid; i < 64 * 27; i += 256) w_s[i] = w[b * 64 * 27 + i];
    if (tid < 64) b_s[tid] = bias[b * 64 + tid];
    __syncthreads();
    const int y = tid >> 4, xc = tid & 15;
    float r[27];
    #pragma unroll
    for (int c = 0; c < 3; c++)
        #pragma unroll
        for (int ky = 0; ky < 3; ky++)
            #pragma unroll
            for (int kx = 0; kx < 3; kx++)
                r[(c * 3 + ky) * 3 + kx] = in_s[c][y + ky][xc + kx];
    const int gy = ty0 + y, gx = tx0 + xc;
    uint16_t* dst = h1 + ((size_t)(b * 4096 + gy * 64 + gx)) * 64;
    for (int oc0 = 0; oc0 < 64; oc0 += 4) {
        float a4[4];
        #pragma unroll
        for (int u = 0; u < 4; u++) {
            float acc = b_s[oc0 + u];
            #pragma unroll
            for (int k = 0; k < 27; k++) acc = fmaf(r[k], w_s[(oc0 + u) * 27 + k], acc);
            a4[u] = fmaxf(acc, 0.f);
        }
        ushort4 p;
        p.x = f2bf(a4[0]); p.y = f2bf(a4[1]); p.z = f2bf(a4[2]); p.w = f2bf(a4[3]);
        *reinterpret_cast<ushort4*>(dst + oc0) = p;
    }
}

// ------- weight prep: w[b][oc][ci][3][3] f32 -> wp[b][kk][oc][ci] bf16 -----
template<int COUT, int CIN>
__global__ __launch_bounds__(256) void prep_w(
    const float* __restrict__ w, uint16_t* __restrict__ wp)
{
    const int idx = blockIdx.x * 256 + threadIdx.x;
    constexpr int total = NB * COUT * CIN;
    if (idx >= total) return;
    const int ci = idx % CIN;
    const int t  = idx / CIN;
    const int oc = t % COUT;
    const int b  = t / COUT;
    const float* s = w + (size_t)idx * 9;
    #pragma unroll
    for (int k = 0; k < 9; k++)
        wp[((size_t)(b * 9 + k) * COUT + oc) * CIN + ci] = f2bf(s[k]);
}

// ---------------- MFMA implicit-GEMM conv, 3x3 SAME, ReLU ------------------
// Block: 64 oc x 8 rows; 4 waves, 2 rows each. Per wave per kk: 4 A-frags
// (2 rows x 2 px-halves) + 2 B-frags -> 8 v_mfma_f32_32x32x16_bf16.
// K-step = 16 ci, double-buffered dynamic LDS (2 x 39936 B + 1 KB red).
// Staging via global_load_lds(16B), sigma-swizzled SOURCE (linear dest);
// reads apply same sigma g^=((g>>3)&7) on 16B granules. Input rows 66 sites
// (px -1..64); rows y0-1..y0+8 at LDS rows 0..9. Halo/pad lanes -> zero page.
template<int CIN, int COUT, bool POOL>
__global__ __launch_bounds__(256, 2) void conv_mfma(
    const uint16_t* __restrict__ in, const uint16_t* __restrict__ wp,
    const float* __restrict__ bias, uint16_t* __restrict__ out,
    float* __restrict__ partial, const float* __restrict__ zp)
{
    constexpr int IN_G  = 1320;              // 10 rows * 66 sites * 2 granules
    constexpr int IN_GA = 1344;              // padded to 64-chunk multiple
    constexpr int W_G   = 1152;              // 9 kk * 64 oc * 2 granules
    constexpr int IN_B  = IN_GA * 16;        // 21504 B
    constexpr int BUF_B = IN_B + W_G * 16;   // 39936 B
    extern __shared__ __align__(16) char sm[];
    const int b = blockIdx.z;
    const int ocbase = blockIdx.y * 64;
    const int y0 = blockIdx.x * 8;
    const int tid = threadIdx.x;
    const int wv = tid >> 6, l = tid & 63, q = l >> 5, ln = l & 31;
    const int NK = CIN / 16;

    // ---- staging source pointers (sigma-swizzled global addresses)
    const uint16_t* src_in[6];
    #pragma unroll
    for (int i = 0; i < 6; i++) {
        const int gp = i * 256 + tid;
        const int g = gp ^ ((gp >> 3) & 7);
        const int qq = g & 1, site = g >> 1;
        const int row = site / 66, px = site - row * 66;
        const int gy = y0 - 1 + row, gx = px - 1;
        const bool valid = (row < 10) && ((unsigned)gy < 64u) && ((unsigned)gx < 64u);
        src_in[i] = valid ? in + ((size_t)((b * 64 + gy) * 64 + gx) * CIN + qq * 8)
                          : (const uint16_t*)zp;
    }
    const uint16_t* src_w[5];
    #pragma unroll
    for (int i = 0; i < 5; i++) {
        const int gp = i * 256 + tid;
        const int g = gp ^ ((gp >> 3) & 7);
        const int qq = g & 1, kk = g >> 7, oc = (g >> 1) & 63;
        src_w[i] = wp + ((size_t)(b * 9 + kk) * COUT + ocbase + oc) * CIN + qq * 8;
    }

    // ---- swizzled LDS read offsets: t = dr+ky (4 rows), kx, h (px half)
    int aoff[4][3][2];
    #pragma unroll
    for (int t = 0; t < 4; t++)
        #pragma unroll
        for (int kx = 0; kx < 3; kx++)
            #pragma unroll
            for (int h = 0; h < 2; h++) {
                const int g = ((wv * 2 + t) * 66 + h * 32 + ln + kx) * 2 + q;
                aoff[t][kx][h] = (g ^ ((g >> 3) & 7)) * 16;
            }
    const int gb = ln * 2 + q;
    const int boff = (gb ^ ((gb >> 3) & 7)) * 16;   // n=1 at +1024

    f32x16 aA0, aA1, aB0, aB1, aC0, aC1, aD0, aD1;  // [dr][h] x [n]
    {
        const float bv0 = bias[b * COUT + ocbase + ln];
        const float bv1 = bias[b * COUT + ocbase + 32 + ln];
        #pragma unroll
        for (int r = 0; r < 16; r++) {
            aA0[r] = bv0; aB0[r] = bv0; aC0[r] = bv0; aD0[r] = bv0;
            aA1[r] = bv1; aB1[r] = bv1; aC1[r] = bv1; aD1[r] = bv1;
        }
    }

    auto stage = [&](char* base, int k) {
        const int koff = k * 16;
        #pragma unroll
        for (int i = 0; i < 6; i++) {
            const int g0 = i * 256 + wv * 64;
            if (g0 < IN_GA) gload16(src_in[i] + koff, base + g0 * 16);
        }
        #pragma unroll
        for (int i = 0; i < 5; i++) {
            const int g0 = i * 256 + wv * 64;
            if (g0 < W_G) gload16(src_w[i] + koff, base + IN_B + g0 * 16);
        }
    };

    stage(sm, 0);
    asm volatile("s_waitcnt vmcnt(0)" ::: "memory");
    __syncthreads();

    for (int k = 0; k < NK; k++) {
        char* cb = sm + (k & 1) * BUF_B;
        if (k + 1 < NK) stage(sm + ((k + 1) & 1) * BUF_B, k + 1);
        #pragma unroll
        for (int ky = 0; ky < 3; ky++)
            #pragma unroll
            for (int kx = 0; kx < 3; kx++) {
                const int kk = ky * 3 + kx;
                short8 fA = *(const short8*)(cb + aoff[ky + 0][kx][0]);  // dr0 h0
                short8 fB = *(const short8*)(cb + aoff[ky + 0][kx][1]);  // dr0 h1
                short8 fC = *(const short8*)(cb + aoff[ky + 1][kx][0]);  // dr1 h0
                short8 fD = *(const short8*)(cb + aoff[ky + 1][kx][1]);  // dr1 h1
                const char* bw = cb + IN_B + kk * 2048 + boff;
                short8 b0 = *(const short8*)(bw);
                short8 b1 = *(const short8*)(bw + 1024);
                __builtin_amdgcn_s_setprio(1);
                aA0 = __builtin_amdgcn_mfma_f32_32x32x16_bf16(fA, b0, aA0, 0, 0, 0);
                aB0 = __builtin_amdgcn_mfma_f32_32x32x16_bf16(fB, b0, aB0, 0, 0, 0);
                aC0 = __builtin_amdgcn_mfma_f32_32x32x16_bf16(fC, b0, aC0, 0, 0, 0);
                aD0 = __builtin_amdgcn_mfma_f32_32x32x16_bf16(fD, b0, aD0, 0, 0, 0);
                aA1 = __builtin_amdgcn_mfma_f32_32x32x16_bf16(fA, b1, aA1, 0, 0, 0);
                aB1 = __builtin_amdgcn_mfma_f32_32x32x16_bf16(fB, b1, aB1, 0, 0, 0);
                aC1 = __builtin_amdgcn_mfma_f32_32x32x16_bf16(fC, b1, aC1, 0, 0, 0);
                aD1 = __builtin_amdgcn_mfma_f32_32x32x16_bf16(fD, b1, aD1, 0, 0, 0);
                __builtin_amdgcn_s_setprio(0);
            }
        asm volatile("s_waitcnt vmcnt(0)" ::: "memory");
        __syncthreads();
    }

    if (!POOL) {
        #pragma unroll
        for (int r = 0; r < 16; r++) {
            const int pxr = (r & 3) + 8 * (r >> 2) + 4 * q;
            const int y0w = y0 + wv * 2;
            uint16_t* dA = out + (size_t)((b * 64 + y0w) * 64 + pxr) * COUT + ocbase;
            uint16_t* dB = out + (size_t)((b * 64 + y0w) * 64 + 32 + pxr) * COUT + ocbase;
            uint16_t* dC = out + (size_t)((b * 64 + y0w + 1) * 64 + pxr) * COUT + ocbase;
            uint16_t* dD = out + (size_t)((b * 64 + y0w + 1) * 64 + 32 + pxr) * COUT + ocbase;
            dA[ln]      = f2bf(fmaxf(aA0[r], 0.f));
            dA[32 + ln] = f2bf(fmaxf(aA1[r], 0.f));
            dB[ln]      = f2bf(fmaxf(aB0[r], 0.f));
            dB[32 + ln] = f2bf(fmaxf(aB1[r], 0.f));
            dC[ln]      = f2bf(fmaxf(aC0[r], 0.f));
            dC[32 + ln] = f2bf(fmaxf(aC1[r], 0.f));
            dD[ln]      = f2bf(fmaxf(aD0[r], 0.f));
            dD[32 + ln] = f2bf(fmaxf(aD1[r], 0.f));
        }
    } else {
        float* red = (float*)(sm + 2 * BUF_B);
        float s0 = 0.f, s1 = 0.f;
        #pragma unroll
        for (int r = 0; r < 16; r++) {
            s0 += fmaxf(aA0[r], 0.f) + fmaxf(aB0[r], 0.f)
                + fmaxf(aC0[r], 0.f) + fmaxf(aD0[r], 0.f);
            s1 += fmaxf(aA1[r], 0.f) + fmaxf(aB1[r], 0.f)
                + fmaxf(aC1[r], 0.f) + fmaxf(aD1[r], 0.f);
        }
        s0 += __shfl_xor(s0, 32);
        s1 += __shfl_xor(s1, 32);
        if (q == 0) {
            red[wv * 64 + ln] = s0;
            red[wv * 64 + 32 + ln] = s1;
        }
        __syncthreads();
        if (tid < 64) {
            float t = red[tid] + red[64 + tid] + red[128 + tid] + red[192 + tid];
            partial[(size_t)(b * 256 + ocbase + tid) * 8 + blockIdx.x] = t;
        }
    }
}

// ------- pooled mean + outer product with fc weight + bias4 ----------------
__global__ void fc_k(const float* __restrict__ partial,
                     const float* __restrict__ fcw,
                     const float* __restrict__ b4, float* __restrict__ out)
{
    const int b = blockIdx.x, c = threadIdx.x;   // 32 x 256
    const float* p = partial + (size_t)(b * 256 + c) * 8;
    float s = 0.f;
    #pragma unroll
    for (int i = 0; i < 8; i++) s += p[i];
    const float pooled = s * (1.f / 4096.f);
    #pragma unroll
    for (int o = 0; o < 10; o++)
        out[(b * 256 + c) * 10 + o] = fmaf(pooled, fcw[b * 10 + o], b4[b * 10 + o]);
}

extern "C" void kernel_launch(void* const* d_in, const int* in_sizes, int n_in,
                              void* d_out, int out_size, void* d_ws, size_t ws_size,
                              hipStream_t stream)
{
    const float* x   = (const float*)d_in[0];
    const float* w1  = (const float*)d_in[1];
    const float* w2  = (const float*)d_in[2];
    const float* w3  = (const float*)d_in[3];
    const float* fcw = (const float*)d_in[4];
    const float* b1  = (const float*)d_in[5];
    const float* b2  = (const float*)d_in[6];
    const float* b3  = (const float*)d_in[7];
    const float* b4  = (const float*)d_in[8];
    char* ws = (char*)d_ws;
    // Lifetime-aliased layout (peak ~52.7 MB, proven in R2/R3):
    //   h2  [0, 32Mi)        (32,4096,128) bf16, live conv2..conv3
    //   h1  [32Mi, 48Mi)     (32,4096,64)  bf16, live conv1..conv2
    //   wp2 [48Mi, +4.5Mi)   bf16 w2^T, live prep2..conv2
    //   wp3 [32Mi, +18Mi)    (over dead h1) written AFTER conv2
    //   partial [50Mi, +256K) f32, written by conv3
    uint16_t* h2      = (uint16_t*)(ws);
    uint16_t* h1      = (uint16_t*)(ws + 33554432);
    uint16_t* wp2     = (uint16_t*)(ws + 50331648);
    uint16_t* wp3     = (uint16_t*)(ws + 33554432);
    float*    partial = (float*)   (ws + 52428800);
    const float* zp   = (const float*)d_out;

    constexpr int DYN_LDS = 2 * 39936 + 1024;   // 80896 B
    static bool attr_done = false;
    if (!attr_done) {   // host-side attribute set; not a stream op (capture-safe)
        hipFuncSetAttribute((const void*)&conv_mfma<64, 128, false>,
                            hipFuncAttributeMaxDynamicSharedMemorySize, DYN_LDS);
        hipFuncSetAttribute((const void*)&conv_mfma<128, 256, true>,
                            hipFuncAttributeMaxDynamicSharedMemorySize, DYN_LDS);
        attr_done = true;
    }

    hipMemsetAsync(d_out, 0, 65536, stream);
    prep_w<128, 64><<<1024, 256, 0, stream>>>(w2, wp2);
    conv1_k<<<dim3(16, NB), 256, 0, stream>>>(x, w1, b1, h1);
    conv_mfma<64, 128, false><<<dim3(8, 2, NB), 256, DYN_LDS, stream>>>(h1, wp2, b2, h2, nullptr, zp);
    prep_w<256, 128><<<4096, 256, 0, stream>>>(w3, wp3);   // after conv2: h1/wp2 dead
    conv_mfma<128, 256, true><<<dim3(8, 4, NB), 256, DYN_LDS, stream>>>(h2, wp3, b3, nullptr, partial, zp);
    fc_k<<<NB, 256, 0, stream>>>(partial, fcw, b4, (float*)d_out);
}

// Round 5
// 163.041 us; speedup vs baseline: 1.1654x; 1.1654x over previous
//
#include <hip/hip_runtime.h>
#include <stdint.h>

typedef __attribute__((ext_vector_type(8))) short short8;
typedef __attribute__((ext_vector_type(16))) float f32x16;

#define NB 32

__device__ __forceinline__ float bf2f(uint16_t v) {
    return __uint_as_float(((uint32_t)v) << 16);
}
__device__ __forceinline__ uint16_t f2bf(float f) {
    uint32_t u = __float_as_uint(f);
    u += 0x7fffu + ((u >> 16) & 1u);   // RNE
    return (uint16_t)(u >> 16);
}

// async global(16B) -> LDS, linear dest (wave-uniform base + lane*16)
__device__ __forceinline__ void gload16(const void* g, void* l) {
    __builtin_amdgcn_global_load_lds(
        (const __attribute__((address_space(1))) uint32_t*)g,
        (__attribute__((address_space(3))) uint32_t*)l, 16, 0, 0);
}

// ---------------- conv1: Cin=3, Cout=64, 3x3 SAME, ReLU, NHWC bf16 out -----
__global__ __launch_bounds__(256) void conv1_k(
    const float* __restrict__ x, const float* __restrict__ w,
    const float* __restrict__ bias, uint16_t* __restrict__ h1)
{
    const int b = blockIdx.y;
    const int tile = blockIdx.x;                 // 16 tiles of 16x16
    const int ty0 = (tile >> 2) * 16, tx0 = (tile & 3) * 16;
    __shared__ float in_s[3][18][18];
    __shared__ float w_s[64 * 27];
    __shared__ float b_s[64];
    const int tid = threadIdx.x;
    for (int i = tid; i < 3 * 18 * 18; i += 256) {
        int c = i / 324, r2 = i % 324, yy = r2 / 18, xx = r2 % 18;
        int gy = ty0 - 1 + yy, gx = tx0 - 1 + xx;
        float v = 0.f;
        if (gy >= 0 && gy < 64 && gx >= 0 && gx < 64)
            v = x[((b * 3 + c) * 64 + gy) * 64 + gx];
        in_s[c][yy][xx] = v;
    }
    for (int i = tid; i < 64 * 27; i += 256) w_s[i] = w[b * 64 * 27 + i];
    if (tid < 64) b_s[tid] = bias[b * 64 + tid];
    __syncthreads();
    const int y = tid >> 4, xc = tid & 15;
    float r[27];
    #pragma unroll
    for (int c = 0; c < 3; c++)
        #pragma unroll
        for (int ky = 0; ky < 3; ky++)
            #pragma unroll
            for (int kx = 0; kx < 3; kx++)
                r[(c * 3 + ky) * 3 + kx] = in_s[c][y + ky][xc + kx];
    const int gy = ty0 + y, gx = tx0 + xc;
    uint16_t* dst = h1 + ((size_t)(b * 4096 + gy * 64 + gx)) * 64;
    for (int oc0 = 0; oc0 < 64; oc0 += 4) {
        float a4[4];
        #pragma unroll
        for (int u = 0; u < 4; u++) {
            float acc = b_s[oc0 + u];
            #pragma unroll
            for (int k = 0; k < 27; k++) acc = fmaf(r[k], w_s[(oc0 + u) * 27 + k], acc);
            a4[u] = fmaxf(acc, 0.f);
        }
        ushort4 p;
        p.x = f2bf(a4[0]); p.y = f2bf(a4[1]); p.z = f2bf(a4[2]); p.w = f2bf(a4[3]);
        *reinterpret_cast<ushort4*>(dst + oc0) = p;
    }
}

// ------- weight prep: w[b][oc][ci][3][3] f32 -> wp[b][kk][oc][ci] bf16 -----
template<int COUT, int CIN>
__global__ __launch_bounds__(256) void prep_w(
    const float* __restrict__ w, uint16_t* __restrict__ wp)
{
    const int idx = blockIdx.x * 256 + threadIdx.x;
    constexpr int total = NB * COUT * CIN;
    if (idx >= total) return;
    const int ci = idx % CIN;
    const int t  = idx / CIN;
    const int oc = t % COUT;
    const int b  = t / COUT;
    const float* s = w + (size_t)idx * 9;
    #pragma unroll
    for (int k = 0; k < 9; k++)
        wp[((size_t)(b * 9 + k) * COUT + oc) * CIN + ci] = f2bf(s[k]);
}

// ---------------- MFMA implicit-GEMM conv, 3x3 SAME, ReLU ------------------
// Block: 64 oc x 8 rows; 4 waves, 2 rows each. Per wave per kk: 4 A-frags
// (2 rows x 2 px-halves) + 2 B-frags -> 8 v_mfma_f32_32x32x16_bf16.
// K-step = 16 ci, double-buffered dynamic LDS; staging via global_load_lds
// with sigma-swizzled SOURCE addresses (linear dest), sigma g^=((g>>3)&7)
// on 16B granules applied on reads.
// Grid is 1D, XCD-PINNED: all blocks of batch b land on XCD b%8 (assumes
// round-robin wg->XCD = L%8) so stripe/oc-block siblings share one L2 and
// staging re-reads become L2 hits instead of HBM/L3 fetches.
template<int CIN, int COUT, int OCBLKS, bool POOL>
__global__ __launch_bounds__(256, 2) void conv_mfma(
    const uint16_t* __restrict__ in, const uint16_t* __restrict__ wp,
    const float* __restrict__ bias, uint16_t* __restrict__ out,
    float* __restrict__ partial, const float* __restrict__ zp)
{
    constexpr int IN_G  = 1320;              // 10 rows * 66 sites * 2 granules
    constexpr int IN_GA = 1344;              // padded to 64-chunk multiple
    constexpr int W_G   = 1152;              // 9 kk * 64 oc * 2 granules
    constexpr int IN_B  = IN_GA * 16;        // 21504 B
    constexpr int BUF_B = IN_B + W_G * 16;   // 39936 B
    constexpr int P     = OCBLKS * 8;        // blocks per batch (stripes=8)
    extern __shared__ __align__(16) char sm[];

    // ---- XCD-pinned decode: batch = (jj/P)*8 + (L&7)
    const int L   = blockIdx.x;
    const int xcd = L & 7;
    const int jj  = L >> 3;
    const int b   = (jj / P) * 8 + xcd;
    const int inner = jj % P;
    const int ocbase = (inner >> 3) * 64;
    const int stripe = inner & 7;
    const int y0 = stripe * 8;

    const int tid = threadIdx.x;
    const int wv = tid >> 6, l = tid & 63, q = l >> 5, ln = l & 31;
    const int NK = CIN / 16;

    // ---- staging source pointers (sigma-swizzled global addresses)
    const uint16_t* src_in[6];
    #pragma unroll
    for (int i = 0; i < 6; i++) {
        const int gp = i * 256 + tid;
        const int g = gp ^ ((gp >> 3) & 7);
        const int qq = g & 1, site = g >> 1;
        const int row = site / 66, px = site - row * 66;
        const int gy = y0 - 1 + row, gx = px - 1;
        const bool valid = (row < 10) && ((unsigned)gy < 64u) && ((unsigned)gx < 64u);
        src_in[i] = valid ? in + ((size_t)((b * 64 + gy) * 64 + gx) * CIN + qq * 8)
                          : (const uint16_t*)zp;
    }
    const uint16_t* src_w[5];
    #pragma unroll
    for (int i = 0; i < 5; i++) {
        const int gp = i * 256 + tid;
        const int g = gp ^ ((gp >> 3) & 7);
        const int qq = g & 1, kk = g >> 7, oc = (g >> 1) & 63;
        src_w[i] = wp + ((size_t)(b * 9 + kk) * COUT + ocbase + oc) * CIN + qq * 8;
    }

    // ---- swizzled LDS read offsets: t = dr+ky (4 rows), kx, h (px half)
    int aoff[4][3][2];
    #pragma unroll
    for (int t = 0; t < 4; t++)
        #pragma unroll
        for (int kx = 0; kx < 3; kx++)
            #pragma unroll
            for (int h = 0; h < 2; h++) {
                const int g = ((wv * 2 + t) * 66 + h * 32 + ln + kx) * 2 + q;
                aoff[t][kx][h] = (g ^ ((g >> 3) & 7)) * 16;
            }
    const int gb = ln * 2 + q;
    const int boff = (gb ^ ((gb >> 3) & 7)) * 16;   // n=1 at +1024

    f32x16 aA0, aA1, aB0, aB1, aC0, aC1, aD0, aD1;  // [dr][h] x [n]
    {
        const float bv0 = bias[b * COUT + ocbase + ln];
        const float bv1 = bias[b * COUT + ocbase + 32 + ln];
        #pragma unroll
        for (int r = 0; r < 16; r++) {
            aA0[r] = bv0; aB0[r] = bv0; aC0[r] = bv0; aD0[r] = bv0;
            aA1[r] = bv1; aB1[r] = bv1; aC1[r] = bv1; aD1[r] = bv1;
        }
    }

    auto stage = [&](char* base, int k) {
        const int koff = k * 16;
        #pragma unroll
        for (int i = 0; i < 6; i++) {
            const int g0 = i * 256 + wv * 64;
            if (g0 < IN_GA) gload16(src_in[i] + koff, base + g0 * 16);
        }
        #pragma unroll
        for (int i = 0; i < 5; i++) {
            const int g0 = i * 256 + wv * 64;
            if (g0 < W_G) gload16(src_w[i] + koff, base + IN_B + g0 * 16);
        }
    };

    stage(sm, 0);
    asm volatile("s_waitcnt vmcnt(0)" ::: "memory");
    __syncthreads();

    for (int k = 0; k < NK; k++) {
        char* cb = sm + (k & 1) * BUF_B;
        if (k + 1 < NK) stage(sm + ((k + 1) & 1) * BUF_B, k + 1);
        #pragma unroll
        for (int ky = 0; ky < 3; ky++)
            #pragma unroll
            for (int kx = 0; kx < 3; kx++) {
                const int kk = ky * 3 + kx;
                short8 fA = *(const short8*)(cb + aoff[ky + 0][kx][0]);  // dr0 h0
                short8 fB = *(const short8*)(cb + aoff[ky + 0][kx][1]);  // dr0 h1
                short8 fC = *(const short8*)(cb + aoff[ky + 1][kx][0]);  // dr1 h0
                short8 fD = *(const short8*)(cb + aoff[ky + 1][kx][1]);  // dr1 h1
                const char* bw = cb + IN_B + kk * 2048 + boff;
                short8 b0 = *(const short8*)(bw);
                short8 b1 = *(const short8*)(bw + 1024);
                __builtin_amdgcn_s_setprio(1);
                aA0 = __builtin_amdgcn_mfma_f32_32x32x16_bf16(fA, b0, aA0, 0, 0, 0);
                aB0 = __builtin_amdgcn_mfma_f32_32x32x16_bf16(fB, b0, aB0, 0, 0, 0);
                aC0 = __builtin_amdgcn_mfma_f32_32x32x16_bf16(fC, b0, aC0, 0, 0, 0);
                aD0 = __builtin_amdgcn_mfma_f32_32x32x16_bf16(fD, b0, aD0, 0, 0, 0);
                aA1 = __builtin_amdgcn_mfma_f32_32x32x16_bf16(fA, b1, aA1, 0, 0, 0);
                aB1 = __builtin_amdgcn_mfma_f32_32x32x16_bf16(fB, b1, aB1, 0, 0, 0);
                aC1 = __builtin_amdgcn_mfma_f32_32x32x16_bf16(fC, b1, aC1, 0, 0, 0);
                aD1 = __builtin_amdgcn_mfma_f32_32x32x16_bf16(fD, b1, aD1, 0, 0, 0);
                __builtin_amdgcn_s_setprio(0);
            }
        asm volatile("s_waitcnt vmcnt(0)" ::: "memory");
        __syncthreads();
    }

    if (!POOL) {
        #pragma unroll
        for (int r = 0; r < 16; r++) {
            const int pxr = (r & 3) + 8 * (r >> 2) + 4 * q;
            const int y0w = y0 + wv * 2;
            uint16_t* dA = out + (size_t)((b * 64 + y0w) * 64 + pxr) * COUT + ocbase;
            uint16_t* dB = out + (size_t)((b * 64 + y0w) * 64 + 32 + pxr) * COUT + ocbase;
            uint16_t* dC = out + (size_t)((b * 64 + y0w + 1) * 64 + pxr) * COUT + ocbase;
            uint16_t* dD = out + (size_t)((b * 64 + y0w + 1) * 64 + 32 + pxr) * COUT + ocbase;
            dA[ln]      = f2bf(fmaxf(aA0[r], 0.f));
            dA[32 + ln] = f2bf(fmaxf(aA1[r], 0.f));
            dB[ln]      = f2bf(fmaxf(aB0[r], 0.f));
            dB[32 + ln] = f2bf(fmaxf(aB1[r], 0.f));
            dC[ln]      = f2bf(fmaxf(aC0[r], 0.f));
            dC[32 + ln] = f2bf(fmaxf(aC1[r], 0.f));
            dD[ln]      = f2bf(fmaxf(aD0[r], 0.f));
            dD[32 + ln] = f2bf(fmaxf(aD1[r], 0.f));
        }
    } else {
        float* red = (float*)(sm + 2 * BUF_B);
        float s0 = 0.f, s1 = 0.f;
        #pragma unroll
        for (int r = 0; r < 16; r++) {
            s0 += fmaxf(aA0[r], 0.f) + fmaxf(aB0[r], 0.f)
                + fmaxf(aC0[r], 0.f) + fmaxf(aD0[r], 0.f);
            s1 += fmaxf(aA1[r], 0.f) + fmaxf(aB1[r], 0.f)
                + fmaxf(aC1[r], 0.f) + fmaxf(aD1[r], 0.f);
        }
        s0 += __shfl_xor(s0, 32);
        s1 += __shfl_xor(s1, 32);
        if (q == 0) {
            red[wv * 64 + ln] = s0;
            red[wv * 64 + 32 + ln] = s1;
        }
        __syncthreads();
        if (tid < 64) {
            float t = red[tid] + red[64 + tid] + red[128 + tid] + red[192 + tid];
            partial[(size_t)(b * 256 + ocbase + tid) * 8 + stripe] = t;
        }
    }
}

// ------- pooled mean + outer product with fc weight + bias4 ----------------
__global__ void fc_k(const float* __restrict__ partial,
                     const float* __restrict__ fcw,
                     const float* __restrict__ b4, float* __restrict__ out)
{
    const int b = blockIdx.x, c = threadIdx.x;   // 32 x 256
    const float* p = partial + (size_t)(b * 256 + c) * 8;
    float s = 0.f;
    #pragma unroll
    for (int i = 0; i < 8; i++) s += p[i];
    const float pooled = s * (1.f / 4096.f);
    #pragma unroll
    for (int o = 0; o < 10; o++)
        out[(b * 256 + c) * 10 + o] = fmaf(pooled, fcw[b * 10 + o], b4[b * 10 + o]);
}

extern "C" void kernel_launch(void* const* d_in, const int* in_sizes, int n_in,
                              void* d_out, int out_size, void* d_ws, size_t ws_size,
                              hipStream_t stream)
{
    const float* x   = (const float*)d_in[0];
    const float* w1  = (const float*)d_in[1];
    const float* w2  = (const float*)d_in[2];
    const float* w3  = (const float*)d_in[3];
    const float* fcw = (const float*)d_in[4];
    const float* b1  = (const float*)d_in[5];
    const float* b2  = (const float*)d_in[6];
    const float* b3  = (const float*)d_in[7];
    const float* b4  = (const float*)d_in[8];
    char* ws = (char*)d_ws;
    // Lifetime-aliased layout (peak ~52.7 MB, proven in R2/R3):
    //   h2  [0, 32Mi)        (32,4096,128) bf16, live conv2..conv3
    //   h1  [32Mi, 48Mi)     (32,4096,64)  bf16, live conv1..conv2
    //   wp2 [48Mi, +4.5Mi)   bf16 w2^T, live prep2..conv2
    //   wp3 [32Mi, +18Mi)    (over dead h1) written AFTER conv2
    //   partial [50Mi, +256K) f32, written by conv3
    uint16_t* h2      = (uint16_t*)(ws);
    uint16_t* h1      = (uint16_t*)(ws + 33554432);
    uint16_t* wp2     = (uint16_t*)(ws + 50331648);
    uint16_t* wp3     = (uint16_t*)(ws + 33554432);
    float*    partial = (float*)   (ws + 52428800);
    const float* zp   = (const float*)d_out;

    constexpr int DYN_LDS = 2 * 39936 + 1024;   // 80896 B
    static bool attr_done = false;
    if (!attr_done) {   // host-side attribute set; not a stream op (capture-safe)
        hipFuncSetAttribute((const void*)&conv_mfma<64, 128, 2, false>,
                            hipFuncAttributeMaxDynamicSharedMemorySize, DYN_LDS);
        hipFuncSetAttribute((const void*)&conv_mfma<128, 256, 4, true>,
                            hipFuncAttributeMaxDynamicSharedMemorySize, DYN_LDS);
        attr_done = true;
    }

    hipMemsetAsync(d_out, 0, 65536, stream);
    prep_w<128, 64><<<1024, 256, 0, stream>>>(w2, wp2);
    conv1_k<<<dim3(16, NB), 256, 0, stream>>>(x, w1, b1, h1);
    conv_mfma<64, 128, 2, false><<<NB * 16, 256, DYN_LDS, stream>>>(h1, wp2, b2, h2, nullptr, zp);
    prep_w<256, 128><<<4096, 256, 0, stream>>>(w3, wp3);   // after conv2: h1/wp2 dead
    conv_mfma<128, 256, 4, true><<<NB * 32, 256, DYN_LDS, stream>>>(h2, wp3, b3, nullptr, partial, zp);
    fc_k<<<NB, 256, 0, stream>>>(partial, fcw, b4, (float*)d_out);
}

// Round 6
// 123.217 us; speedup vs baseline: 1.5420x; 1.3232x over previous
//
#include <hip/hip_runtime.h>
#include <stdint.h>

typedef __attribute__((ext_vector_type(8))) short short8;
typedef __attribute__((ext_vector_type(16))) float f32x16;

#define NB 32

__device__ __forceinline__ float bf2f(uint16_t v) {
    return __uint_as_float(((uint32_t)v) << 16);
}
__device__ __forceinline__ uint16_t f2bf(float f) {
    uint32_t u = __float_as_uint(f);
    u += 0x7fffu + ((u >> 16) & 1u);   // RNE
    return (uint16_t)(u >> 16);
}

// async global(16B) -> LDS, linear dest (wave-uniform base + lane*16)
__device__ __forceinline__ void gload16(const void* g, void* l) {
    __builtin_amdgcn_global_load_lds(
        (const __attribute__((address_space(1))) uint32_t*)g,
        (__attribute__((address_space(3))) uint32_t*)l, 16, 0, 0);
}

// ------- weight prep item: w[b][oc][ci][3][3] f32 -> wp[b][kk][oc][ci] bf16
template<int COUT, int CIN>
__device__ __forceinline__ void prep_w_item(int idx, const float* __restrict__ w,
                                            uint16_t* __restrict__ wp)
{
    const int ci = idx % CIN;
    const int t  = idx / CIN;
    const int oc = t % COUT;
    const int b  = t / COUT;
    const float* s = w + (size_t)idx * 9;
    #pragma unroll
    for (int k = 0; k < 9; k++)
        wp[((size_t)(b * 9 + k) * COUT + oc) * CIN + ci] = f2bf(s[k]);
}

// ------- standalone w3 prep (aliased-ws mode: must run AFTER conv2) --------
__global__ __launch_bounds__(256) void prep_w3_k(
    const float* __restrict__ w, uint16_t* __restrict__ wp)
{
    const int idx = blockIdx.x * 256 + threadIdx.x;
    if (idx < NB * 256 * 128) prep_w_item<256, 128>(idx, w, wp);
}

// ------- fused prep: zero-page + x->NHWC16 bf16 + w1 + w2 (+ w3) -----------
// segments (flat): [0,4096) zp float4 zeros | [..+131072) x sites |
// [..+18432) w1 (b,k,oc) items | [..+262144) w2 items | [..+1048576) w3 items
template<bool DO_W3>
__global__ __launch_bounds__(256) void prep_all(
    const float* __restrict__ x,  const float* __restrict__ w1,
    const float* __restrict__ w2, const float* __restrict__ w3,
    uint16_t* __restrict__ xp,  uint16_t* __restrict__ wp1,
    uint16_t* __restrict__ wp2, uint16_t* __restrict__ wp3,
    float* __restrict__ zp)
{
    int idx = blockIdx.x * 256 + threadIdx.x;
    if (idx < 4096) {                          // zero page (64 KB)
        ((float4*)zp)[idx] = make_float4(0.f, 0.f, 0.f, 0.f);
        return;
    }
    idx -= 4096;
    if (idx < 131072) {                        // x: NCHW f32 -> NHWC(ci=16) bf16
        const int xc = idx & 63, y = (idx >> 6) & 63, b = idx >> 12;
        const float* s = x + (size_t)b * 3 * 4096 + y * 64 + xc;
        const uint16_t v0 = f2bf(s[0]), v1 = f2bf(s[4096]), v2 = f2bf(s[8192]);
        short8 lo = {(short)v0, (short)v1, (short)v2, 0, 0, 0, 0, 0};
        short8 hi = {0, 0, 0, 0, 0, 0, 0, 0};
        uint16_t* d = xp + (size_t)idx * 16;
        *(short8*)d = lo;
        *(short8*)(d + 8) = hi;
        return;
    }
    idx -= 131072;
    if (idx < 18432) {                         // w1 -> wp1[b][kk][oc][ci=16]
        const int oc = idx & 63, k = (idx >> 6) % 9, b = idx / 576;
        const uint16_t v0 = f2bf(w1[((size_t)(b * 64 + oc) * 3 + 0) * 9 + k]);
        const uint16_t v1 = f2bf(w1[((size_t)(b * 64 + oc) * 3 + 1) * 9 + k]);
        const uint16_t v2 = f2bf(w1[((size_t)(b * 64 + oc) * 3 + 2) * 9 + k]);
        short8 lo = {(short)v0, (short)v1, (short)v2, 0, 0, 0, 0, 0};
        short8 hi = {0, 0, 0, 0, 0, 0, 0, 0};
        uint16_t* d = wp1 + ((size_t)(b * 9 + k) * 64 + oc) * 16;
        *(short8*)d = lo;
        *(short8*)(d + 8) = hi;
        return;
    }
    idx -= 18432;
    if (idx < 262144) {                        // w2
        prep_w_item<128, 64>(idx, w2, wp2);
        return;
    }
    if (!DO_W3) return;
    idx -= 262144;
    if (idx < 1048576) prep_w_item<256, 128>(idx, w3, wp3);
}

// ---------------- MFMA implicit-GEMM conv, 3x3 SAME, ReLU ------------------
// Block: 64 oc x 8 rows; 4 waves, 2 rows each. Per wave per kk: 4 A-frags
// (2 rows x 2 px-halves) + 2 B-frags -> 8 v_mfma_f32_32x32x16_bf16.
// K-step = 16 ci, double-buffered dynamic LDS; staging via global_load_lds
// with sigma-swizzled SOURCE addresses (linear dest), sigma g^=((g>>3)&7)
// on 16B granules applied on reads.
// Grid is 1D, XCD-PINNED: all blocks of batch b land on XCD b%8 (assumes
// round-robin wg->XCD = L%8) so stripe/oc-block siblings share one L2 and
// staging re-reads become L2 hits instead of HBM/L3 fetches.
template<int CIN, int COUT, int OCBLKS, bool POOL>
__global__ __launch_bounds__(256, 2) void conv_mfma(
    const uint16_t* __restrict__ in, const uint16_t* __restrict__ wp,
    const float* __restrict__ bias, uint16_t* __restrict__ out,
    float* __restrict__ partial, const float* __restrict__ zp)
{
    constexpr int IN_G  = 1320;              // 10 rows * 66 sites * 2 granules
    constexpr int IN_GA = 1344;              // padded to 64-chunk multiple
    constexpr int W_G   = 1152;              // 9 kk * 64 oc * 2 granules
    constexpr int IN_B  = IN_GA * 16;        // 21504 B
    constexpr int BUF_B = IN_B + W_G * 16;   // 39936 B
    constexpr int P     = OCBLKS * 8;        // blocks per batch (stripes=8)
    extern __shared__ __align__(16) char sm[];

    // ---- XCD-pinned decode: batch = (jj/P)*8 + (L&7)
    const int L   = blockIdx.x;
    const int xcd = L & 7;
    const int jj  = L >> 3;
    const int b   = (jj / P) * 8 + xcd;
    const int inner = jj % P;
    const int ocbase = (inner >> 3) * 64;
    const int stripe = inner & 7;
    const int y0 = stripe * 8;

    const int tid = threadIdx.x;
    const int wv = tid >> 6, l = tid & 63, q = l >> 5, ln = l & 31;
    const int NK = CIN / 16;

    // ---- staging source pointers (sigma-swizzled global addresses)
    const uint16_t* src_in[6];
    #pragma unroll
    for (int i = 0; i < 6; i++) {
        const int gp = i * 256 + tid;
        const int g = gp ^ ((gp >> 3) & 7);
        const int qq = g & 1, site = g >> 1;
        const int row = site / 66, px = site - row * 66;
        const int gy = y0 - 1 + row, gx = px - 1;
        const bool valid = (row < 10) && ((unsigned)gy < 64u) && ((unsigned)gx < 64u);
        src_in[i] = valid ? in + ((size_t)((b * 64 + gy) * 64 + gx) * CIN + qq * 8)
                          : (const uint16_t*)zp;
    }
    const uint16_t* src_w[5];
    #pragma unroll
    for (int i = 0; i < 5; i++) {
        const int gp = i * 256 + tid;
        const int g = gp ^ ((gp >> 3) & 7);
        const int qq = g & 1, kk = g >> 7, oc = (g >> 1) & 63;
        src_w[i] = wp + ((size_t)(b * 9 + kk) * COUT + ocbase + oc) * CIN + qq * 8;
    }

    // ---- swizzled LDS read offsets: t = dr+ky (4 rows), kx, h (px half)
    int aoff[4][3][2];
    #pragma unroll
    for (int t = 0; t < 4; t++)
        #pragma unroll
        for (int kx = 0; kx < 3; kx++)
            #pragma unroll
            for (int h = 0; h < 2; h++) {
                const int g = ((wv * 2 + t) * 66 + h * 32 + ln + kx) * 2 + q;
                aoff[t][kx][h] = (g ^ ((g >> 3) & 7)) * 16;
            }
    const int gb = ln * 2 + q;
    const int boff = (gb ^ ((gb >> 3) & 7)) * 16;   // n=1 at +1024

    f32x16 aA0, aA1, aB0, aB1, aC0, aC1, aD0, aD1;  // [dr][h] x [n]
    {
        const float bv0 = bias[b * COUT + ocbase + ln];
        const float bv1 = bias[b * COUT + ocbase + 32 + ln];
        #pragma unroll
        for (int r = 0; r < 16; r++) {
            aA0[r] = bv0; aB0[r] = bv0; aC0[r] = bv0; aD0[r] = bv0;
            aA1[r] = bv1; aB1[r] = bv1; aC1[r] = bv1; aD1[r] = bv1;
        }
    }

    auto stage = [&](char* base, int k) {
        const int koff = k * 16;
        #pragma unroll
        for (int i = 0; i < 6; i++) {
            const int g0 = i * 256 + wv * 64;
            if (g0 < IN_GA) gload16(src_in[i] + koff, base + g0 * 16);
        }
        #pragma unroll
        for (int i = 0; i < 5; i++) {
            const int g0 = i * 256 + wv * 64;
            if (g0 < W_G) gload16(src_w[i] + koff, base + IN_B + g0 * 16);
        }
    };

    stage(sm, 0);
    asm volatile("s_waitcnt vmcnt(0)" ::: "memory");
    __syncthreads();

    for (int k = 0; k < NK; k++) {
        char* cb = sm + (k & 1) * BUF_B;
        if (k + 1 < NK) stage(sm + ((k + 1) & 1) * BUF_B, k + 1);
        #pragma unroll
        for (int ky = 0; ky < 3; ky++)
            #pragma unroll
            for (int kx = 0; kx < 3; kx++) {
                const int kk = ky * 3 + kx;
                short8 fA = *(const short8*)(cb + aoff[ky + 0][kx][0]);  // dr0 h0
                short8 fB = *(const short8*)(cb + aoff[ky + 0][kx][1]);  // dr0 h1
                short8 fC = *(const short8*)(cb + aoff[ky + 1][kx][0]);  // dr1 h0
                short8 fD = *(const short8*)(cb + aoff[ky + 1][kx][1]);  // dr1 h1
                const char* bw = cb + IN_B + kk * 2048 + boff;
                short8 b0 = *(const short8*)(bw);
                short8 b1 = *(const short8*)(bw + 1024);
                __builtin_amdgcn_s_setprio(1);
                aA0 = __builtin_amdgcn_mfma_f32_32x32x16_bf16(fA, b0, aA0, 0, 0, 0);
                aB0 = __builtin_amdgcn_mfma_f32_32x32x16_bf16(fB, b0, aB0, 0, 0, 0);
                aC0 = __builtin_amdgcn_mfma_f32_32x32x16_bf16(fC, b0, aC0, 0, 0, 0);
                aD0 = __builtin_amdgcn_mfma_f32_32x32x16_bf16(fD, b0, aD0, 0, 0, 0);
                aA1 = __builtin_amdgcn_mfma_f32_32x32x16_bf16(fA, b1, aA1, 0, 0, 0);
                aB1 = __builtin_amdgcn_mfma_f32_32x32x16_bf16(fB, b1, aB1, 0, 0, 0);
                aC1 = __builtin_amdgcn_mfma_f32_32x32x16_bf16(fC, b1, aC1, 0, 0, 0);
                aD1 = __builtin_amdgcn_mfma_f32_32x32x16_bf16(fD, b1, aD1, 0, 0, 0);
                __builtin_amdgcn_s_setprio(0);
            }
        asm volatile("s_waitcnt vmcnt(0)" ::: "memory");
        __syncthreads();
    }

    if (!POOL) {
        #pragma unroll
        for (int r = 0; r < 16; r++) {
            const int pxr = (r & 3) + 8 * (r >> 2) + 4 * q;
            const int y0w = y0 + wv * 2;
            uint16_t* dA = out + (size_t)((b * 64 + y0w) * 64 + pxr) * COUT + ocbase;
            uint16_t* dB = out + (size_t)((b * 64 + y0w) * 64 + 32 + pxr) * COUT + ocbase;
            uint16_t* dC = out + (size_t)((b * 64 + y0w + 1) * 64 + pxr) * COUT + ocbase;
            uint16_t* dD = out + (size_t)((b * 64 + y0w + 1) * 64 + 32 + pxr) * COUT + ocbase;
            dA[ln]      = f2bf(fmaxf(aA0[r], 0.f));
            dA[32 + ln] = f2bf(fmaxf(aA1[r], 0.f));
            dB[ln]      = f2bf(fmaxf(aB0[r], 0.f));
            dB[32 + ln] = f2bf(fmaxf(aB1[r], 0.f));
            dC[ln]      = f2bf(fmaxf(aC0[r], 0.f));
            dC[32 + ln] = f2bf(fmaxf(aC1[r], 0.f));
            dD[ln]      = f2bf(fmaxf(aD0[r], 0.f));
            dD[32 + ln] = f2bf(fmaxf(aD1[r], 0.f));
        }
    } else {
        float* red = (float*)(sm + 2 * BUF_B);
        float s0 = 0.f, s1 = 0.f;
        #pragma unroll
        for (int r = 0; r < 16; r++) {
            s0 += fmaxf(aA0[r], 0.f) + fmaxf(aB0[r], 0.f)
                + fmaxf(aC0[r], 0.f) + fmaxf(aD0[r], 0.f);
            s1 += fmaxf(aA1[r], 0.f) + fmaxf(aB1[r], 0.f)
                + fmaxf(aC1[r], 0.f) + fmaxf(aD1[r], 0.f);
        }
        s0 += __shfl_xor(s0, 32);
        s1 += __shfl_xor(s1, 32);
        if (q == 0) {
            red[wv * 64 + ln] = s0;
            red[wv * 64 + 32 + ln] = s1;
        }
        __syncthreads();
        if (tid < 64) {
            float t = red[tid] + red[64 + tid] + red[128 + tid] + red[192 + tid];
            partial[(size_t)(b * 256 + ocbase + tid) * 8 + stripe] = t;
        }
    }
}

// ------- pooled mean + outer product with fc weight + bias4 ----------------
__global__ void fc_k(const float* __restrict__ partial,
                     const float* __restrict__ fcw,
                     const float* __restrict__ b4, float* __restrict__ out)
{
    const int b = blockIdx.x, c = threadIdx.x;   // 32 x 256
    const float* p = partial + (size_t)(b * 256 + c) * 8;
    float s = 0.f;
    #pragma unroll
    for (int i = 0; i < 8; i++) s += p[i];
    const float pooled = s * (1.f / 4096.f);
    #pragma unroll
    for (int o = 0; o < 10; o++)
        out[(b * 256 + c) * 10 + o] = fmaf(pooled, fcw[b * 10 + o], b4[b * 10 + o]);
}

extern "C" void kernel_launch(void* const* d_in, const int* in_sizes, int n_in,
                              void* d_out, int out_size, void* d_ws, size_t ws_size,
                              hipStream_t stream)
{
    const float* x   = (const float*)d_in[0];
    const float* w1  = (const float*)d_in[1];
    const float* w2  = (const float*)d_in[2];
    const float* w3  = (const float*)d_in[3];
    const float* fcw = (const float*)d_in[4];
    const float* b1  = (const float*)d_in[5];
    const float* b2  = (const float*)d_in[6];
    const float* b3  = (const float*)d_in[7];
    const float* b4  = (const float*)d_in[8];
    char* ws = (char*)d_ws;
    // Common regions:
    //   xp  [0, 4Mi)        (32,4096,16) bf16  — lives in h2 space, dead @conv2
    //   wp1 [4Mi, +576Ki)   bf16 w1^T(ci pad 16) — also h2 space, dead @conv2
    //   h2  [0, 32Mi)       (32,4096,128) bf16, written by conv2
    //   h1  [32Mi, 48Mi)    (32,4096,64)  bf16, conv1m -> conv2
    //   wp2 [48Mi, +4.5Mi)  bf16 w2^T
    // Aliased mode (ws proven >= 55.05 MB in R2):
    //   wp3 [32Mi, +18Mi)   over dead h1, written AFTER conv2 (serial bubble)
    //   partial [50Mi,+256K) inside dead wp2
    // Big-ws mode (ws >= 74186752): wp3/partial get own space; prep_w3 fused
    // into prep_all (no bubble).
    uint16_t* xp  = (uint16_t*)(ws);
    uint16_t* wp1 = (uint16_t*)(ws + 4194304);
    uint16_t* h2  = (uint16_t*)(ws);
    uint16_t* h1  = (uint16_t*)(ws + 33554432);
    uint16_t* wp2 = (uint16_t*)(ws + 50331648);
    const bool big_ws = ws_size >= 74186752u;
    uint16_t* wp3     = (uint16_t*)(ws + (big_ws ? 55050240u : 33554432u));
    float*    partial = (float*)   (ws + (big_ws ? 73924608u : 52428800u));
    float*    zp      = (float*)d_out;   // first 64 KB zeroed by prep_all

    constexpr int DYN_LDS = 2 * 39936 + 1024;   // 80896 B
    static bool attr_done = false;
    if (!attr_done) {   // host-side attribute set; not a stream op (capture-safe)
        hipFuncSetAttribute((const void*)&conv_mfma<16, 64, 1, false>,
                            hipFuncAttributeMaxDynamicSharedMemorySize, DYN_LDS);
        hipFuncSetAttribute((const void*)&conv_mfma<64, 128, 2, false>,
                            hipFuncAttributeMaxDynamicSharedMemorySize, DYN_LDS);
        hipFuncSetAttribute((const void*)&conv_mfma<128, 256, 4, true>,
                            hipFuncAttributeMaxDynamicSharedMemorySize, DYN_LDS);
        attr_done = true;
    }

    if (big_ws) {
        prep_all<true><<<5720, 256, 0, stream>>>(x, w1, w2, w3, xp, wp1, wp2, wp3, zp);
    } else {
        prep_all<false><<<1624, 256, 0, stream>>>(x, w1, w2, w3, xp, wp1, wp2, wp3, zp);
    }
    conv_mfma<16, 64, 1, false><<<NB * 8, 256, DYN_LDS, stream>>>(xp, wp1, b1, h1, nullptr, zp);
    conv_mfma<64, 128, 2, false><<<NB * 16, 256, DYN_LDS, stream>>>(h1, wp2, b2, h2, nullptr, zp);
    if (!big_ws)
        prep_w3_k<<<4096, 256, 0, stream>>>(w3, wp3);   // h1/wp2 dead after conv2
    conv_mfma<128, 256, 4, true><<<NB * 32, 256, DYN_LDS, stream>>>(h2, wp3, b3, nullptr, partial, zp);
    fc_k<<<NB, 256, 0, stream>>>(partial, fcw, b4, (float*)d_out);
}

// Round 7
// 119.808 us; speedup vs baseline: 1.5859x; 1.0284x over previous
//
#include <hip/hip_runtime.h>
#include <stdint.h>

typedef __attribute__((ext_vector_type(8))) short short8;
typedef __attribute__((ext_vector_type(16))) float f32x16;

#define NB 32

__device__ __forceinline__ float bf2f(uint16_t v) {
    return __uint_as_float(((uint32_t)v) << 16);
}
__device__ __forceinline__ uint16_t f2bf(float f) {
    uint32_t u = __float_as_uint(f);
    u += 0x7fffu + ((u >> 16) & 1u);   // RNE
    return (uint16_t)(u >> 16);
}

// async global(16B) -> LDS, linear dest (wave-uniform base + lane*16)
__device__ __forceinline__ void gload16(const void* g, void* l) {
    __builtin_amdgcn_global_load_lds(
        (const __attribute__((address_space(1))) uint32_t*)g,
        (__attribute__((address_space(3))) uint32_t*)l, 16, 0, 0);
}

// ------- weight prep item: w[b][oc][ci][3][3] f32 -> wp[b][kk][oc][ci] bf16
template<int COUT, int CIN>
__device__ __forceinline__ void prep_w_item(int idx, const float* __restrict__ w,
                                            uint16_t* __restrict__ wp)
{
    const int ci = idx % CIN;
    const int t  = idx / CIN;
    const int oc = t % COUT;
    const int b  = t / COUT;
    const float* s = w + (size_t)idx * 9;
    #pragma unroll
    for (int k = 0; k < 9; k++)
        wp[((size_t)(b * 9 + k) * COUT + oc) * CIN + ci] = f2bf(s[k]);
}

// ------- standalone w3 prep (aliased-ws mode: must run AFTER conv2) --------
__global__ __launch_bounds__(256) void prep_w3_k(
    const float* __restrict__ w, uint16_t* __restrict__ wp)
{
    const int idx = blockIdx.x * 256 + threadIdx.x;
    if (idx < NB * 256 * 128) prep_w_item<256, 128>(idx, w, wp);
}

// ------- fused prep: zero-page + x->NHWC16 bf16 + w1 + w2 (+ w3) -----------
template<bool DO_W3>
__global__ __launch_bounds__(256) void prep_all(
    const float* __restrict__ x,  const float* __restrict__ w1,
    const float* __restrict__ w2, const float* __restrict__ w3,
    uint16_t* __restrict__ xp,  uint16_t* __restrict__ wp1,
    uint16_t* __restrict__ wp2, uint16_t* __restrict__ wp3,
    float* __restrict__ zp)
{
    int idx = blockIdx.x * 256 + threadIdx.x;
    if (idx < 4096) {                          // zero page (64 KB)
        ((float4*)zp)[idx] = make_float4(0.f, 0.f, 0.f, 0.f);
        return;
    }
    idx -= 4096;
    if (idx < 131072) {                        // x: NCHW f32 -> NHWC(ci=16) bf16
        const int xc = idx & 63, y = (idx >> 6) & 63, b = idx >> 12;
        const float* s = x + (size_t)b * 3 * 4096 + y * 64 + xc;
        const uint16_t v0 = f2bf(s[0]), v1 = f2bf(s[4096]), v2 = f2bf(s[8192]);
        short8 lo = {(short)v0, (short)v1, (short)v2, 0, 0, 0, 0, 0};
        short8 hi = {0, 0, 0, 0, 0, 0, 0, 0};
        uint16_t* d = xp + (size_t)idx * 16;
        *(short8*)d = lo;
        *(short8*)(d + 8) = hi;
        return;
    }
    idx -= 131072;
    if (idx < 18432) {                         // w1 -> wp1[b][kk][oc][ci=16]
        const int oc = idx & 63, k = (idx >> 6) % 9, b = idx / 576;
        const uint16_t v0 = f2bf(w1[((size_t)(b * 64 + oc) * 3 + 0) * 9 + k]);
        const uint16_t v1 = f2bf(w1[((size_t)(b * 64 + oc) * 3 + 1) * 9 + k]);
        const uint16_t v2 = f2bf(w1[((size_t)(b * 64 + oc) * 3 + 2) * 9 + k]);
        short8 lo = {(short)v0, (short)v1, (short)v2, 0, 0, 0, 0, 0};
        short8 hi = {0, 0, 0, 0, 0, 0, 0, 0};
        uint16_t* d = wp1 + ((size_t)(b * 9 + k) * 64 + oc) * 16;
        *(short8*)d = lo;
        *(short8*)(d + 8) = hi;
        return;
    }
    idx -= 18432;
    if (idx < 262144) {                        // w2
        prep_w_item<128, 64>(idx, w2, wp2);
        return;
    }
    if (!DO_W3) return;
    idx -= 262144;
    if (idx < 1048576) prep_w_item<256, 128>(idx, w3, wp3);
}

// ---------------- MFMA implicit-GEMM conv, 3x3 SAME, ReLU ------------------
// Block: 64 oc x 8 rows; 4 waves, 2 rows each. Per wave per kk: 4 A-frags
// (2 rows x 2 px-halves) + 2 B-frags -> 8 v_mfma_f32_32x32x16_bf16.
// K-step = 16 ci, double-buffered dynamic LDS; staging via global_load_lds
// with sigma-swizzled SOURCE addresses (linear dest), sigma g^=((g>>3)&7)
// on 16B granules applied on reads. Grid 1D, XCD-pinned (batch b -> XCD b%8).
// R7: ONE setprio pair around the whole per-K-step compute section (the
// previous per-kk pairs were scheduler region boundaries that serialized
// ds_read vs MFMA).
template<int CIN, int COUT, int OCBLKS, bool POOL>
__global__ __launch_bounds__(256, 2) void conv_mfma(
    const uint16_t* __restrict__ in, const uint16_t* __restrict__ wp,
    const float* __restrict__ bias, uint16_t* __restrict__ out,
    float* __restrict__ partial, const float* __restrict__ zp)
{
    constexpr int IN_GA = 1344;              // 10*66*2=1320 granules, pad 1344
    constexpr int W_G   = 1152;              // 9 kk * 64 oc * 2 granules
    constexpr int IN_B  = IN_GA * 16;        // 21504 B
    constexpr int BUF_B = IN_B + W_G * 16;   // 39936 B
    constexpr int P     = OCBLKS * 8;        // blocks per batch (stripes=8)
    extern __shared__ __align__(16) char sm[];

    // ---- XCD-pinned decode: batch = (jj/P)*8 + (L&7)
    const int L   = blockIdx.x;
    const int xcd = L & 7;
    const int jj  = L >> 3;
    const int b   = (jj / P) * 8 + xcd;
    const int inner = jj % P;
    const int ocbase = (inner >> 3) * 64;
    const int stripe = inner & 7;
    const int y0 = stripe * 8;

    const int tid = threadIdx.x;
    const int wv = tid >> 6, l = tid & 63, q = l >> 5, ln = l & 31;
    const int NK = CIN / 16;

    // ---- staging source pointers (sigma-swizzled global addresses)
    const uint16_t* src_in[6];
    #pragma unroll
    for (int i = 0; i < 6; i++) {
        const int gp = i * 256 + tid;
        const int g = gp ^ ((gp >> 3) & 7);
        const int qq = g & 1, site = g >> 1;
        const int row = site / 66, px = site - row * 66;
        const int gy = y0 - 1 + row, gx = px - 1;
        const bool valid = (row < 10) && ((unsigned)gy < 64u) && ((unsigned)gx < 64u);
        src_in[i] = valid ? in + ((size_t)((b * 64 + gy) * 64 + gx) * CIN + qq * 8)
                          : (const uint16_t*)zp;
    }
    const uint16_t* src_w[5];
    #pragma unroll
    for (int i = 0; i < 5; i++) {
        const int gp = i * 256 + tid;
        const int g = gp ^ ((gp >> 3) & 7);
        const int qq = g & 1, kk = g >> 7, oc = (g >> 1) & 63;
        src_w[i] = wp + ((size_t)(b * 9 + kk) * COUT + ocbase + oc) * CIN + qq * 8;
    }

    // ---- swizzled LDS read offsets: t = dr+ky (4 rows), kx, h (px half)
    int aoff[4][3][2];
    #pragma unroll
    for (int t = 0; t < 4; t++)
        #pragma unroll
        for (int kx = 0; kx < 3; kx++)
            #pragma unroll
            for (int h = 0; h < 2; h++) {
                const int g = ((wv * 2 + t) * 66 + h * 32 + ln + kx) * 2 + q;
                aoff[t][kx][h] = (g ^ ((g >> 3) & 7)) * 16;
            }
    const int gb = ln * 2 + q;
    const int boff = (gb ^ ((gb >> 3) & 7)) * 16;   // n=1 at +1024

    f32x16 aA0, aA1, aB0, aB1, aC0, aC1, aD0, aD1;  // [dr][h] x [n]
    {
        const float bv0 = bias[b * COUT + ocbase + ln];
        const float bv1 = bias[b * COUT + ocbase + 32 + ln];
        #pragma unroll
        for (int r = 0; r < 16; r++) {
            aA0[r] = bv0; aB0[r] = bv0; aC0[r] = bv0; aD0[r] = bv0;
            aA1[r] = bv1; aB1[r] = bv1; aC1[r] = bv1; aD1[r] = bv1;
        }
    }

    auto stage = [&](char* base, int k) {
        const int koff = k * 16;
        #pragma unroll
        for (int i = 0; i < 6; i++) {
            const int g0 = i * 256 + wv * 64;
            if (g0 < IN_GA) gload16(src_in[i] + koff, base + g0 * 16);
        }
        #pragma unroll
        for (int i = 0; i < 5; i++) {
            const int g0 = i * 256 + wv * 64;
            if (g0 < W_G) gload16(src_w[i] + koff, base + IN_B + g0 * 16);
        }
    };

    stage(sm, 0);
    asm volatile("s_waitcnt vmcnt(0)" ::: "memory");
    __syncthreads();

    for (int k = 0; k < NK; k++) {
        char* cb = sm + (k & 1) * BUF_B;
        if (k + 1 < NK) stage(sm + ((k + 1) & 1) * BUF_B, k + 1);
        __builtin_amdgcn_s_setprio(1);
        #pragma unroll
        for (int ky = 0; ky < 3; ky++)
            #pragma unroll
            for (int kx = 0; kx < 3; kx++) {
                const int kk = ky * 3 + kx;
                short8 fA = *(const short8*)(cb + aoff[ky + 0][kx][0]);  // dr0 h0
                short8 fB = *(const short8*)(cb + aoff[ky + 0][kx][1]);  // dr0 h1
                short8 fC = *(const short8*)(cb + aoff[ky + 1][kx][0]);  // dr1 h0
                short8 fD = *(const short8*)(cb + aoff[ky + 1][kx][1]);  // dr1 h1
                const char* bw = cb + IN_B + kk * 2048 + boff;
                short8 b0 = *(const short8*)(bw);
                short8 b1 = *(const short8*)(bw + 1024);
                aA0 = __builtin_amdgcn_mfma_f32_32x32x16_bf16(fA, b0, aA0, 0, 0, 0);
                aB0 = __builtin_amdgcn_mfma_f32_32x32x16_bf16(fB, b0, aB0, 0, 0, 0);
                aC0 = __builtin_amdgcn_mfma_f32_32x32x16_bf16(fC, b0, aC0, 0, 0, 0);
                aD0 = __builtin_amdgcn_mfma_f32_32x32x16_bf16(fD, b0, aD0, 0, 0, 0);
                aA1 = __builtin_amdgcn_mfma_f32_32x32x16_bf16(fA, b1, aA1, 0, 0, 0);
                aB1 = __builtin_amdgcn_mfma_f32_32x32x16_bf16(fB, b1, aB1, 0, 0, 0);
                aC1 = __builtin_amdgcn_mfma_f32_32x32x16_bf16(fC, b1, aC1, 0, 0, 0);
                aD1 = __builtin_amdgcn_mfma_f32_32x32x16_bf16(fD, b1, aD1, 0, 0, 0);
            }
        __builtin_amdgcn_s_setprio(0);
        asm volatile("s_waitcnt vmcnt(0)" ::: "memory");
        __syncthreads();
    }

    if (!POOL) {
        #pragma unroll
        for (int r = 0; r < 16; r++) {
            const int pxr = (r & 3) + 8 * (r >> 2) + 4 * q;
            const int y0w = y0 + wv * 2;
            uint16_t* dA = out + (size_t)((b * 64 + y0w) * 64 + pxr) * COUT + ocbase;
            uint16_t* dB = out + (size_t)((b * 64 + y0w) * 64 + 32 + pxr) * COUT + ocbase;
            uint16_t* dC = out + (size_t)((b * 64 + y0w + 1) * 64 + pxr) * COUT + ocbase;
            uint16_t* dD = out + (size_t)((b * 64 + y0w + 1) * 64 + 32 + pxr) * COUT + ocbase;
            dA[ln]      = f2bf(fmaxf(aA0[r], 0.f));
            dA[32 + ln] = f2bf(fmaxf(aA1[r], 0.f));
            dB[ln]      = f2bf(fmaxf(aB0[r], 0.f));
            dB[32 + ln] = f2bf(fmaxf(aB1[r], 0.f));
            dC[ln]      = f2bf(fmaxf(aC0[r], 0.f));
            dC[32 + ln] = f2bf(fmaxf(aC1[r], 0.f));
            dD[ln]      = f2bf(fmaxf(aD0[r], 0.f));
            dD[32 + ln] = f2bf(fmaxf(aD1[r], 0.f));
        }
    } else {
        float* red = (float*)(sm + 2 * BUF_B);
        float s0 = 0.f, s1 = 0.f;
        #pragma unroll
        for (int r = 0; r < 16; r++) {
            s0 += fmaxf(aA0[r], 0.f) + fmaxf(aB0[r], 0.f)
                + fmaxf(aC0[r], 0.f) + fmaxf(aD0[r], 0.f);
            s1 += fmaxf(aA1[r], 0.f) + fmaxf(aB1[r], 0.f)
                + fmaxf(aC1[r], 0.f) + fmaxf(aD1[r], 0.f);
        }
        s0 += __shfl_xor(s0, 32);
        s1 += __shfl_xor(s1, 32);
        if (q == 0) {
            red[wv * 64 + ln] = s0;
            red[wv * 64 + 32 + ln] = s1;
        }
        __syncthreads();
        if (tid < 64) {
            float t = red[tid] + red[64 + tid] + red[128 + tid] + red[192 + tid];
            partial[(size_t)(b * 256 + ocbase + tid) * 8 + stripe] = t;
        }
    }
}

// ------- pooled mean + outer product with fc weight + bias4 ----------------
__global__ void fc_k(const float* __restrict__ partial,
                     const float* __restrict__ fcw,
                     const float* __restrict__ b4, float* __restrict__ out)
{
    const int b = blockIdx.x, c = threadIdx.x;   // 32 x 256
    const float* p = partial + (size_t)(b * 256 + c) * 8;
    float s = 0.f;
    #pragma unroll
    for (int i = 0; i < 8; i++) s += p[i];
    const float pooled = s * (1.f / 4096.f);
    #pragma unroll
    for (int o = 0; o < 10; o++)
        out[(b * 256 + c) * 10 + o] = fmaf(pooled, fcw[b * 10 + o], b4[b * 10 + o]);
}

extern "C" void kernel_launch(void* const* d_in, const int* in_sizes, int n_in,
                              void* d_out, int out_size, void* d_ws, size_t ws_size,
                              hipStream_t stream)
{
    const float* x   = (const float*)d_in[0];
    const float* w1  = (const float*)d_in[1];
    const float* w2  = (const float*)d_in[2];
    const float* w3  = (const float*)d_in[3];
    const float* fcw = (const float*)d_in[4];
    const float* b1  = (const float*)d_in[5];
    const float* b2  = (const float*)d_in[6];
    const float* b3  = (const float*)d_in[7];
    const float* b4  = (const float*)d_in[8];
    char* ws = (char*)d_ws;
    // Regions (see R6 notes): xp/wp1 alias dead-until-conv2 h2 space.
    uint16_t* xp  = (uint16_t*)(ws);
    uint16_t* wp1 = (uint16_t*)(ws + 4194304);
    uint16_t* h2  = (uint16_t*)(ws);
    uint16_t* h1  = (uint16_t*)(ws + 33554432);
    uint16_t* wp2 = (uint16_t*)(ws + 50331648);
    const bool big_ws = ws_size >= 74186752u;
    uint16_t* wp3     = (uint16_t*)(ws + (big_ws ? 55050240u : 33554432u));
    float*    partial = (float*)   (ws + (big_ws ? 73924608u : 52428800u));
    float*    zp      = (float*)d_out;   // first 64 KB zeroed by prep_all

    constexpr int DYN_LDS = 2 * 39936 + 1024;   // 80896 B
    static bool attr_done = false;
    if (!attr_done) {   // host-side attribute set; not a stream op (capture-safe)
        hipFuncSetAttribute((const void*)&conv_mfma<16, 64, 1, false>,
                            hipFuncAttributeMaxDynamicSharedMemorySize, DYN_LDS);
        hipFuncSetAttribute((const void*)&conv_mfma<64, 128, 2, false>,
                            hipFuncAttributeMaxDynamicSharedMemorySize, DYN_LDS);
        hipFuncSetAttribute((const void*)&conv_mfma<128, 256, 4, true>,
                            hipFuncAttributeMaxDynamicSharedMemorySize, DYN_LDS);
        attr_done = true;
    }

    if (big_ws) {
        prep_all<true><<<5720, 256, 0, stream>>>(x, w1, w2, w3, xp, wp1, wp2, wp3, zp);
    } else {
        prep_all<false><<<1624, 256, 0, stream>>>(x, w1, w2, w3, xp, wp1, wp2, wp3, zp);
    }
    conv_mfma<16, 64, 1, false><<<NB * 8, 256, DYN_LDS, stream>>>(xp, wp1, b1, h1, nullptr, zp);
    conv_mfma<64, 128, 2, false><<<NB * 16, 256, DYN_LDS, stream>>>(h1, wp2, b2, h2, nullptr, zp);
    if (!big_ws)
        prep_w3_k<<<4096, 256, 0, stream>>>(w3, wp3);   // h1/wp2 dead after conv2
    conv_mfma<128, 256, 4, true><<<NB * 32, 256, DYN_LDS, stream>>>(h2, wp3, b3, nullptr, partial, zp);
    fc_k<<<NB, 256, 0, stream>>>(partial, fcw, b4, (float*)d_out);
}